// Round 1
// 315.373 us; speedup vs baseline: 1.1284x; 1.1284x over previous
//
#include <hip/hip_runtime.h>
#include <hip/hip_bf16.h>
#include <stdint.h>

#define BATCH 16
#define CDIM 1024
#define HWDIM 1024
#define PSTRIDE 2048   // fp16 elements per packed row of the S buffer (4096 B)
#define TILE_E (256 * 64)
#define NTK 16         // K/64 for both GEMMs (K = 1024)

typedef _Float16 half_t;
typedef _Float16 half8 __attribute__((ext_vector_type(8)));
typedef float floatx4 __attribute__((ext_vector_type(4)));

__device__ static inline void gld_lds16(const half_t* g, half_t* l) {
    __builtin_amdgcn_global_load_lds(
        (__attribute__((address_space(1))) void*)(void*)g,
        (__attribute__((address_space(3))) void*)l, 16, 0, 0);
}

__device__ __forceinline__ half8 ld8(const char* p) { return *(const half8*)p; }

template <int MB, int NB>
__device__ __forceinline__ void mfma16(floatx4 (&acc)[8][4],
                                       const half8 (&a4)[4][2],
                                       const half8 (&b2)[2][2]) {
#pragma unroll
    for (int mt = 0; mt < 4; ++mt)
#pragma unroll
        for (int nt = 0; nt < 2; ++nt)
#pragma unroll
            for (int ks = 0; ks < 2; ++ks)
                acc[MB + mt][NB + nt] = __builtin_amdgcn_mfma_f32_16x16x32_f16(
                    a4[mt][ks], b2[nt][ks], acc[MB + mt][NB + nt], 0, 0, 0);
}

// ---------------------------------------------------------------------------
// 256x256x(K=1024) NT fp16 GEMM body, 8-phase schedule (T2+T3+T4+T5).
// 512 threads = 8 waves (2M x 4N). LDS 128 KiB: [2 dbuf][256][64] for A and B.
// Per wave: mt 0..7 -> rows (mt>>2)*128 + wm*64 + (mt&3)*16  (so P0 touches
// only A-half0, P2 only A-half1); nt 0..3 -> cols (nt>>1)*128 + wn*32 +
// (nt&1)*16 (P0 only B-half0, P1 only B-half1).
// Staging schedule (1 half-tile = 2 global_load_lds per thread per phase):
//   P0: A1(t+1) -> buf[t+1]   (region last read at (t-1).P2)
//   P1: B0(t+2) -> buf[t]     (dead after t.P0)
//   P2: A0(t+2) -> buf[t]     (dead after t.P0)
//   P3: B1(t+2) -> buf[t]     (dead after t.P1), then s_waitcnt vmcnt(6):
//       leaves the newest 3 halves (t+2's) in flight, guarantees ALL of
//       tile t+1 has landed before its first read. Never vmcnt(0) mid-loop.
// LDS swizzle: read byte col ^= ((row&7)<<4); global source pre-swizzled the
// same way so the linear global_load_lds dest receives the permuted data
// (both-sides-or-neither, rule #21).
// ---------------------------------------------------------------------------
__device__ __forceinline__ void gemm8p(const half_t* __restrict__ Ag, size_t sA,
                                       const half_t* __restrict__ Bg, size_t sB,
                                       int i0, int j0,
                                       half_t* lA, half_t* lB,
                                       floatx4 (&acc)[8][4]) {
    const int tid = threadIdx.x;
    const int lane = tid & 63;
    const int wave = tid >> 6;
    const int wm = wave >> 2, wn = wave & 3;
    const int fr = lane & 15, hi = lane >> 4;
    const int sw = (fr & 7) << 4;                     // row&7 == fr&7 (row bases are x16)
    const int o0 = fr * 128 + ((hi * 16) ^ sw);       // ks=0 swizzled byte offset
    const int o1 = fr * 128 + ((hi * 16 + 64) ^ sw);  // ks=1

    // staging: thread covers rows r0 and r0+64 of a 128x64 half, one 16B chunk
    // each; chunk column pre-swizzled to invert the read-side XOR.
    const int r0 = tid >> 3;
    const int scol = ((tid & 7) ^ (r0 & 7)) * 8;
    const half_t* pa = Ag + (size_t)(i0 + r0) * sA + scol;
    const half_t* pb = Bg + (size_t)(j0 + r0) * sB + scol;

#pragma unroll
    for (int a = 0; a < 8; ++a)
#pragma unroll
        for (int b = 0; b < 4; ++b) acc[a][b] = (floatx4){0.f, 0.f, 0.f, 0.f};

#define STG_A(tt, h)                                                      \
    do {                                                                  \
        const half_t* g_ = pa + (size_t)(h) * 128 * sA + (tt) * 64;       \
        half_t* l_ = lA + ((tt) & 1) * TILE_E + (h) * 8192 + tid * 8;     \
        gld_lds16(g_, l_);                                                \
        gld_lds16(g_ + 64 * sA, l_ + 4096);                               \
    } while (0)
#define STG_B(tt, h)                                                      \
    do {                                                                  \
        const half_t* g_ = pb + (size_t)(h) * 128 * sB + (tt) * 64;       \
        half_t* l_ = lB + ((tt) & 1) * TILE_E + (h) * 8192 + tid * 8;     \
        gld_lds16(g_, l_);                                                \
        gld_lds16(g_ + 64 * sB, l_ + 4096);                               \
    } while (0)

    // Prologue: tile0 complete (4 halves), then 3 halves of tile1.
    STG_A(0, 0); STG_B(0, 0); STG_A(0, 1); STG_B(0, 1);
    STG_B(1, 0); STG_A(1, 0); STG_B(1, 1);
    asm volatile("s_waitcnt vmcnt(6)" ::: "memory");  // tile0 fully landed
    __builtin_amdgcn_s_barrier();

    half8 af[4][2], bf0[2][2], bf1[2][2];

#pragma unroll 2
    for (int t = 0; t < NTK; ++t) {
        const char* aw = (const char*)(lA + (t & 1) * TILE_E) + wm * 8192;
        const char* bw = (const char*)(lB + (t & 1) * TILE_E) + wn * 4096;

        // ---- P0: ds_read A-half0 + B-half0 frags; stage A1(t+1)
#pragma unroll
        for (int mt = 0; mt < 4; ++mt) {
            af[mt][0] = ld8(aw + mt * 2048 + o0);
            af[mt][1] = ld8(aw + mt * 2048 + o1);
        }
#pragma unroll
        for (int nt = 0; nt < 2; ++nt) {
            bf0[nt][0] = ld8(bw + nt * 2048 + o0);
            bf0[nt][1] = ld8(bw + nt * 2048 + o1);
        }
        if (t + 1 < NTK) STG_A(t + 1, 1);
        __builtin_amdgcn_s_barrier();
        asm volatile("s_waitcnt lgkmcnt(0)" ::: "memory");
        __builtin_amdgcn_s_setprio(1);
        mfma16<0, 0>(acc, af, bf0);
        __builtin_amdgcn_s_setprio(0);
        __builtin_amdgcn_sched_barrier(0);
        __builtin_amdgcn_s_barrier();

        // ---- P1: ds_read B-half1 frags; stage B0(t+2)
#pragma unroll
        for (int nt = 0; nt < 2; ++nt) {
            bf1[nt][0] = ld8(bw + 16384 + nt * 2048 + o0);
            bf1[nt][1] = ld8(bw + 16384 + nt * 2048 + o1);
        }
        if (t + 2 < NTK) STG_B(t + 2, 0);
        __builtin_amdgcn_s_barrier();
        asm volatile("s_waitcnt lgkmcnt(0)" ::: "memory");
        __builtin_amdgcn_s_setprio(1);
        mfma16<0, 2>(acc, af, bf1);
        __builtin_amdgcn_s_setprio(0);
        __builtin_amdgcn_sched_barrier(0);
        __builtin_amdgcn_s_barrier();

        // ---- P2: ds_read A-half1 frags; stage A0(t+2)
#pragma unroll
        for (int mt = 0; mt < 4; ++mt) {
            af[mt][0] = ld8(aw + 16384 + mt * 2048 + o0);
            af[mt][1] = ld8(aw + 16384 + mt * 2048 + o1);
        }
        if (t + 2 < NTK) STG_A(t + 2, 0);
        __builtin_amdgcn_s_barrier();
        asm volatile("s_waitcnt lgkmcnt(0)" ::: "memory");
        __builtin_amdgcn_s_setprio(1);
        mfma16<4, 2>(acc, af, bf1);
        __builtin_amdgcn_s_setprio(0);
        __builtin_amdgcn_sched_barrier(0);
        __builtin_amdgcn_s_barrier();

        // ---- P3: stage B1(t+2); counted vmcnt; MFMA A1 x B0 (both in regs)
        if (t + 2 < NTK) STG_B(t + 2, 1);
        if (t < NTK - 2)
            asm volatile("s_waitcnt vmcnt(6)" ::: "memory");
        else
            asm volatile("s_waitcnt vmcnt(0)" ::: "memory");
        __builtin_amdgcn_s_barrier();
        __builtin_amdgcn_s_setprio(1);
        mfma16<4, 0>(acc, af, bf0);
        __builtin_amdgcn_s_setprio(0);
        __builtin_amdgcn_sched_barrier(0);
        __builtin_amdgcn_s_barrier();
    }
#undef STG_A
#undef STG_B
}

// XCD-chunked bijective swizzle: 256 wg, 32 per XCD = 2 whole batches per XCD
// (4 MB of fp16 panels -> fits the 4 MiB per-XCD L2). nwg % 8 == 0 -> bijective.
__device__ __forceinline__ void tile_coords(int& bz, int& i0, int& j0) {
    const int flat = blockIdx.x + (blockIdx.y << 4);
    const int w = ((flat & 7) << 5) + (flat >> 3);
    bz = w >> 4;
    const int tl = w & 15;
    i0 = (tl & 3) << 8;
    j0 = (tl >> 2) << 8;
}

// ---------------------------------------------------------------------------
// Prep: convert b,c (f32) -> fp16 into scratch (d_out reused as scratch).
// ---------------------------------------------------------------------------
__global__ __launch_bounds__(256) void k_prep(const float* __restrict__ Bm,
                                              const float* __restrict__ Cm,
                                              half_t* __restrict__ dst) {
    const size_t N = (size_t)BATCH * CDIM * HWDIM;
    const float* src = blockIdx.y ? Cm : Bm;
    half_t* d = dst + (size_t)blockIdx.y * N;
    const size_t base = ((size_t)blockIdx.x * 256 + threadIdx.x) * 8;
    float4 f0 = *(const float4*)(src + base);
    float4 f1 = *(const float4*)(src + base + 4);
    half_t h[8];
    h[0] = (half_t)f0.x; h[1] = (half_t)f0.y; h[2] = (half_t)f0.z; h[3] = (half_t)f0.w;
    h[4] = (half_t)f1.x; h[5] = (half_t)f1.y; h[6] = (half_t)f1.z; h[7] = (half_t)f1.w;
    *(uint4*)(d + base) = *(const uint4*)h;
}

// ---------------------------------------------------------------------------
// GEMM1: S[b][i][j] = sum_k bh[b][i][k] * ch[b][j][k]  (NT, fp16 in, f32 out)
// 256^2 8-phase. grid (16,16), block 512.
// ---------------------------------------------------------------------------
__global__ __launch_bounds__(512, 2) void k_gemm1(const half_t* __restrict__ Bh,
                                                  const half_t* __restrict__ Ch,
                                                  float* __restrict__ S) {
    __shared__ half_t lA[2 * TILE_E];
    __shared__ half_t lB[2 * TILE_E];
    int bz, i0, j0;
    tile_coords(bz, i0, j0);

    floatx4 acc[8][4];
    gemm8p(Bh + (size_t)bz * CDIM * HWDIM, HWDIM,
           Ch + (size_t)bz * CDIM * HWDIM, HWDIM, i0, j0, lA, lB, acc);

    float* Sp = S + (size_t)bz * CDIM * CDIM;
    const int lane = threadIdx.x & 63;
    const int wave = threadIdx.x >> 6;
    const int wm = wave >> 2, wn = wave & 3;
    const int er = (lane >> 4) * 4;
    const int ec = lane & 15;
#pragma unroll
    for (int mt = 0; mt < 8; ++mt) {
        const int row0 = i0 + ((mt >> 2) << 7) + wm * 64 + (mt & 3) * 16 + er;
#pragma unroll
        for (int nt = 0; nt < 4; ++nt) {
            const int col = j0 + ((nt >> 1) << 7) + wn * 32 + (nt & 1) * 16 + ec;
            float* dst = Sp + (size_t)row0 * CDIM + col;
#pragma unroll
            for (int r = 0; r < 4; ++r) dst[(size_t)r * CDIM] = acc[mt][nt][r];
        }
    }
}

// ---------------------------------------------------------------------------
// Softmax over each fp32 row of S (1024); packs P (fp16) into the first
// 2048 B of the row. grid 16384, block 256.  (unchanged)
// ---------------------------------------------------------------------------
__global__ __launch_bounds__(256) void k_softmax(float* __restrict__ S) {
    float* rp = S + (size_t)blockIdx.x * CDIM;
    const int tid = threadIdx.x;
    float4 v = ((const float4*)rp)[tid];

    __shared__ float red[256];
    float m = fmaxf(fmaxf(v.x, v.y), fmaxf(v.z, v.w));
    red[tid] = m;
    __syncthreads();
    for (int s = 128; s > 0; s >>= 1) {
        if (tid < s) red[tid] = fmaxf(red[tid], red[tid + s]);
        __syncthreads();
    }
    m = red[0];
    __syncthreads();

    float e0 = __expf(v.x - m), e1 = __expf(v.y - m);
    float e2 = __expf(v.z - m), e3 = __expf(v.w - m);
    red[tid] = e0 + e1 + e2 + e3;
    __syncthreads();
    for (int s = 128; s > 0; s >>= 1) {
        if (tid < s) red[tid] += red[tid + s];
        __syncthreads();
    }
    const float inv = 1.0f / red[0];

    half_t p[4];
    p[0] = (half_t)(e0 * inv);
    p[1] = (half_t)(e1 * inv);
    p[2] = (half_t)(e2 * inv);
    p[3] = (half_t)(e3 * inv);
    ((uint2*)rp)[tid] = *(const uint2*)p;
}

// ---------------------------------------------------------------------------
// Transpose a[b] (C x HW, f32) -> fp16 At rows in the dead half of each packed
// S row (offset +1024 fp16). Runs AFTER softmax. grid (16,16,16). (unchanged)
// ---------------------------------------------------------------------------
__global__ __launch_bounds__(256) void k_transpose(const float* __restrict__ A,
                                                   half_t* __restrict__ SP) {
    const int bz = blockIdx.z;
    const int t0 = blockIdx.x * 64;  // HW block
    const int j0 = blockIdx.y * 64;  // C block
    const float* Ap = A + (size_t)bz * CDIM * HWDIM;
    half_t* Atp = SP + (size_t)bz * CDIM * PSTRIDE + 1024;

    __shared__ half_t tile[64][68];
    const int lr = threadIdx.x >> 4;         // 0..15
    const int lc = (threadIdx.x & 15) * 4;   // 0..60
#pragma unroll
    for (int r = 0; r < 4; ++r) {
        const float* src = Ap + (size_t)(j0 + lr + r * 16) * HWDIM + t0 + lc;
        float4 f = *(const float4*)src;
        half_t t4[4];
        t4[0] = (half_t)f.x; t4[1] = (half_t)f.y;
        t4[2] = (half_t)f.z; t4[3] = (half_t)f.w;
        *(uint2*)&tile[lr + r * 16][lc] = *(const uint2*)t4;
    }
    __syncthreads();
#pragma unroll
    for (int r = 0; r < 4; ++r) {
        const int trow = lr + r * 16;
        half_t tmp[4];
#pragma unroll
        for (int e = 0; e < 4; ++e) tmp[e] = tile[lc + e][trow];
        *(uint2*)(Atp + (size_t)(t0 + trow) * PSTRIDE + j0 + lc) = *(uint2*)tmp;
    }
}

// ---------------------------------------------------------------------------
// GEMM2: Out[b][i][t] = sum_j P[b][i][j]*At[b][t][j] + a[b][i][t] (f32 out).
// P and At (fp16) both live in the packed S buffer, row stride PSTRIDE.
// 256^2 8-phase. grid (16,16), block 512.
// ---------------------------------------------------------------------------
__global__ __launch_bounds__(512, 2) void k_gemm2(const half_t* __restrict__ SP,
                                                  const float* __restrict__ Aorig,
                                                  float* __restrict__ Out) {
    __shared__ half_t lA[2 * TILE_E];
    __shared__ half_t lB[2 * TILE_E];
    int bz, i0, t0;
    tile_coords(bz, i0, t0);

    const half_t* Pp = SP + (size_t)bz * CDIM * PSTRIDE;
    const half_t* Bp = Pp + 1024;  // At rows

    floatx4 acc[8][4];
    gemm8p(Pp, PSTRIDE, Bp, PSTRIDE, i0, t0, lA, lB, acc);

    const float* ap = Aorig + (size_t)bz * CDIM * HWDIM;
    float* op = Out + (size_t)bz * CDIM * HWDIM;
    const int lane = threadIdx.x & 63;
    const int wave = threadIdx.x >> 6;
    const int wm = wave >> 2, wn = wave & 3;
    const int er = (lane >> 4) * 4;
    const int ec = lane & 15;
#pragma unroll
    for (int mt = 0; mt < 8; ++mt) {
        const int row0 = i0 + ((mt >> 2) << 7) + wm * 64 + (mt & 3) * 16 + er;
#pragma unroll
        for (int nt = 0; nt < 4; ++nt) {
            const int col = t0 + ((nt >> 1) << 7) + wn * 32 + (nt & 1) * 16 + ec;
#pragma unroll
            for (int r = 0; r < 4; ++r) {
                const size_t idx = (size_t)(row0 + r) * HWDIM + col;
                op[idx] = acc[mt][nt][r] + ap[idx];
            }
        }
    }
}

extern "C" void kernel_launch(void* const* d_in, const int* in_sizes, int n_in,
                              void* d_out, int out_size, void* d_ws, size_t ws_size,
                              hipStream_t stream) {
    const float* a = (const float*)d_in[0];
    const float* b = (const float*)d_in[1];
    const float* c = (const float*)d_in[2];
    float* out = (float*)d_out;

    float* S = (float*)d_ws;            // 64 MB: fp32 scores -> {P | At} packed
    half_t* bc16 = (half_t*)d_out;      // d_out doubles as fp16 scratch for b,c
                                        // (gemm2 fully overwrites it at the end)

    k_prep<<<dim3(8192, 2), 256, 0, stream>>>(b, c, bc16);
    k_gemm1<<<dim3(16, 16), 512, 0, stream>>>(
        bc16, bc16 + (size_t)BATCH * CDIM * HWDIM, S);
    k_softmax<<<dim3(BATCH * CDIM), 256, 0, stream>>>(S);
    k_transpose<<<dim3(16, 16, 16), 256, 0, stream>>>(a, (half_t*)S);
    k_gemm2<<<dim3(16, 16), 512, 0, stream>>>((const half_t*)S, a, out);
}

// Round 2
// 310.803 us; speedup vs baseline: 1.1450x; 1.0147x over previous
//
#include <hip/hip_runtime.h>
#include <hip/hip_bf16.h>
#include <stdint.h>

#define BATCH 16
#define CDIM 1024
#define HWDIM 1024
#define PSTRIDE 2048   // fp16 elements per packed row of the S buffer (4096 B)
#define TILE_E (256 * 64)
#define NTK 16         // K/64 for both GEMMs (K = 1024)

typedef _Float16 half_t;
typedef _Float16 half8 __attribute__((ext_vector_type(8)));
typedef float floatx4 __attribute__((ext_vector_type(4)));

__device__ static inline void gld_lds16(const half_t* g, half_t* l) {
    __builtin_amdgcn_global_load_lds(
        (__attribute__((address_space(1))) void*)(void*)g,
        (__attribute__((address_space(3))) void*)l, 16, 0, 0);
}

__device__ __forceinline__ half8 ld8(const char* p) { return *(const half8*)p; }

template <int MB, int NB>
__device__ __forceinline__ void mfma16(floatx4 (&acc)[8][4],
                                       const half8 (&a4)[4][2],
                                       const half8 (&b2)[2][2]) {
#pragma unroll
    for (int mt = 0; mt < 4; ++mt)
#pragma unroll
        for (int nt = 0; nt < 2; ++nt)
#pragma unroll
            for (int ks = 0; ks < 2; ++ks)
                acc[MB + mt][NB + nt] = __builtin_amdgcn_mfma_f32_16x16x32_f16(
                    a4[mt][ks], b2[nt][ks], acc[MB + mt][NB + nt], 0, 0, 0);
}

// ---------------------------------------------------------------------------
// 256x256x(K=1024) NT fp16 GEMM body, 8-phase schedule (T2+T3+T4+T5).
// (unchanged from round 1 — verified working)
// ---------------------------------------------------------------------------
__device__ __forceinline__ void gemm8p(const half_t* __restrict__ Ag, size_t sA,
                                       const half_t* __restrict__ Bg, size_t sB,
                                       int i0, int j0,
                                       half_t* lA, half_t* lB,
                                       floatx4 (&acc)[8][4]) {
    const int tid = threadIdx.x;
    const int lane = tid & 63;
    const int wave = tid >> 6;
    const int wm = wave >> 2, wn = wave & 3;
    const int fr = lane & 15, hi = lane >> 4;
    const int sw = (fr & 7) << 4;                     // row&7 == fr&7 (row bases are x16)
    const int o0 = fr * 128 + ((hi * 16) ^ sw);       // ks=0 swizzled byte offset
    const int o1 = fr * 128 + ((hi * 16 + 64) ^ sw);  // ks=1

    const int r0 = tid >> 3;
    const int scol = ((tid & 7) ^ (r0 & 7)) * 8;
    const half_t* pa = Ag + (size_t)(i0 + r0) * sA + scol;
    const half_t* pb = Bg + (size_t)(j0 + r0) * sB + scol;

#pragma unroll
    for (int a = 0; a < 8; ++a)
#pragma unroll
        for (int b = 0; b < 4; ++b) acc[a][b] = (floatx4){0.f, 0.f, 0.f, 0.f};

#define STG_A(tt, h)                                                      \
    do {                                                                  \
        const half_t* g_ = pa + (size_t)(h) * 128 * sA + (tt) * 64;       \
        half_t* l_ = lA + ((tt) & 1) * TILE_E + (h) * 8192 + tid * 8;     \
        gld_lds16(g_, l_);                                                \
        gld_lds16(g_ + 64 * sA, l_ + 4096);                               \
    } while (0)
#define STG_B(tt, h)                                                      \
    do {                                                                  \
        const half_t* g_ = pb + (size_t)(h) * 128 * sB + (tt) * 64;       \
        half_t* l_ = lB + ((tt) & 1) * TILE_E + (h) * 8192 + tid * 8;     \
        gld_lds16(g_, l_);                                                \
        gld_lds16(g_ + 64 * sB, l_ + 4096);                               \
    } while (0)

    // Prologue: tile0 complete (4 halves), then 3 halves of tile1.
    STG_A(0, 0); STG_B(0, 0); STG_A(0, 1); STG_B(0, 1);
    STG_B(1, 0); STG_A(1, 0); STG_B(1, 1);
    asm volatile("s_waitcnt vmcnt(6)" ::: "memory");  // tile0 fully landed
    __builtin_amdgcn_s_barrier();

    half8 af[4][2], bf0[2][2], bf1[2][2];

#pragma unroll 2
    for (int t = 0; t < NTK; ++t) {
        const char* aw = (const char*)(lA + (t & 1) * TILE_E) + wm * 8192;
        const char* bw = (const char*)(lB + (t & 1) * TILE_E) + wn * 4096;

        // ---- P0: ds_read A-half0 + B-half0 frags; stage A1(t+1)
#pragma unroll
        for (int mt = 0; mt < 4; ++mt) {
            af[mt][0] = ld8(aw + mt * 2048 + o0);
            af[mt][1] = ld8(aw + mt * 2048 + o1);
        }
#pragma unroll
        for (int nt = 0; nt < 2; ++nt) {
            bf0[nt][0] = ld8(bw + nt * 2048 + o0);
            bf0[nt][1] = ld8(bw + nt * 2048 + o1);
        }
        if (t + 1 < NTK) STG_A(t + 1, 1);
        __builtin_amdgcn_s_barrier();
        asm volatile("s_waitcnt lgkmcnt(0)" ::: "memory");
        __builtin_amdgcn_s_setprio(1);
        mfma16<0, 0>(acc, af, bf0);
        __builtin_amdgcn_s_setprio(0);
        __builtin_amdgcn_sched_barrier(0);
        __builtin_amdgcn_s_barrier();

        // ---- P1: ds_read B-half1 frags; stage B0(t+2)
#pragma unroll
        for (int nt = 0; nt < 2; ++nt) {
            bf1[nt][0] = ld8(bw + 16384 + nt * 2048 + o0);
            bf1[nt][1] = ld8(bw + 16384 + nt * 2048 + o1);
        }
        if (t + 2 < NTK) STG_B(t + 2, 0);
        __builtin_amdgcn_s_barrier();
        asm volatile("s_waitcnt lgkmcnt(0)" ::: "memory");
        __builtin_amdgcn_s_setprio(1);
        mfma16<0, 2>(acc, af, bf1);
        __builtin_amdgcn_s_setprio(0);
        __builtin_amdgcn_sched_barrier(0);
        __builtin_amdgcn_s_barrier();

        // ---- P2: ds_read A-half1 frags; stage A0(t+2)
#pragma unroll
        for (int mt = 0; mt < 4; ++mt) {
            af[mt][0] = ld8(aw + 16384 + mt * 2048 + o0);
            af[mt][1] = ld8(aw + 16384 + mt * 2048 + o1);
        }
        if (t + 2 < NTK) STG_A(t + 2, 0);
        __builtin_amdgcn_s_barrier();
        asm volatile("s_waitcnt lgkmcnt(0)" ::: "memory");
        __builtin_amdgcn_s_setprio(1);
        mfma16<4, 2>(acc, af, bf1);
        __builtin_amdgcn_s_setprio(0);
        __builtin_amdgcn_sched_barrier(0);
        __builtin_amdgcn_s_barrier();

        // ---- P3: stage B1(t+2); counted vmcnt; MFMA A1 x B0 (both in regs)
        if (t + 2 < NTK) STG_B(t + 2, 1);
        if (t < NTK - 2)
            asm volatile("s_waitcnt vmcnt(6)" ::: "memory");
        else
            asm volatile("s_waitcnt vmcnt(0)" ::: "memory");
        __builtin_amdgcn_s_barrier();
        __builtin_amdgcn_s_setprio(1);
        mfma16<4, 0>(acc, af, bf0);
        __builtin_amdgcn_s_setprio(0);
        __builtin_amdgcn_sched_barrier(0);
        __builtin_amdgcn_s_barrier();
    }
#undef STG_A
#undef STG_B
}

// XCD-chunked bijective swizzle: 256 wg, 32 per XCD = 2 whole batches per XCD.
__device__ __forceinline__ void tile_coords(int& bz, int& i0, int& j0) {
    const int flat = blockIdx.x + (blockIdx.y << 4);
    const int w = ((flat & 7) << 5) + (flat >> 3);
    bz = w >> 4;
    const int tl = w & 15;
    i0 = (tl & 3) << 8;
    j0 = (tl >> 2) << 8;
}

// ---------------------------------------------------------------------------
// Prep: convert b,c (f32) -> fp16 into scratch (d_out reused as scratch).
// Grid-stride, contiguous float4-per-lane (1 KB/wave/instr), uint2 stores.
// grid (2048, 2), block 256; 8 iterations/thread.
// ---------------------------------------------------------------------------
__global__ __launch_bounds__(256) void k_prep(const float* __restrict__ Bm,
                                              const float* __restrict__ Cm,
                                              half_t* __restrict__ dst) {
    const size_t N = (size_t)BATCH * CDIM * HWDIM;   // elements per array
    const size_t NV = N / 4;                         // float4 chunks
    const float* src = blockIdx.y ? Cm : Bm;
    half_t* d = dst + (size_t)blockIdx.y * N;
    const size_t stride = (size_t)gridDim.x * 256;
    for (size_t i = (size_t)blockIdx.x * 256 + threadIdx.x; i < NV; i += stride) {
        float4 f = ((const float4*)src)[i];
        half_t h[4];
        h[0] = (half_t)f.x; h[1] = (half_t)f.y;
        h[2] = (half_t)f.z; h[3] = (half_t)f.w;
        ((uint2*)d)[i] = *(const uint2*)h;
    }
}

// ---------------------------------------------------------------------------
// Softmax over each fp32 row of S (1024); packs P (fp16) into the first
// 2048 B of the row. Wave-per-row: 4 waves/block, 16 f32/lane, shuffle
// reductions, zero barriers. grid 4096, block 256.
// ---------------------------------------------------------------------------
__global__ __launch_bounds__(256) void k_softmax(float* __restrict__ S) {
    const int wave = threadIdx.x >> 6;
    const int lane = threadIdx.x & 63;
    float* rp = S + ((size_t)blockIdx.x * 4 + wave) * CDIM;

    float4 v[4];
#pragma unroll
    for (int j = 0; j < 4; ++j) v[j] = ((const float4*)rp)[lane + 64 * j];

    float m = -1e30f;
#pragma unroll
    for (int j = 0; j < 4; ++j)
        m = fmaxf(m, fmaxf(fmaxf(v[j].x, v[j].y), fmaxf(v[j].z, v[j].w)));
#pragma unroll
    for (int off = 32; off > 0; off >>= 1) m = fmaxf(m, __shfl_xor(m, off));

    float e[4][4];
    float s = 0.f;
#pragma unroll
    for (int j = 0; j < 4; ++j) {
        e[j][0] = __expf(v[j].x - m); e[j][1] = __expf(v[j].y - m);
        e[j][2] = __expf(v[j].z - m); e[j][3] = __expf(v[j].w - m);
        s += e[j][0] + e[j][1] + e[j][2] + e[j][3];
    }
#pragma unroll
    for (int off = 32; off > 0; off >>= 1) s += __shfl_xor(s, off);
    const float inv = 1.0f / s;

#pragma unroll
    for (int j = 0; j < 4; ++j) {
        half_t p[4];
        p[0] = (half_t)(e[j][0] * inv); p[1] = (half_t)(e[j][1] * inv);
        p[2] = (half_t)(e[j][2] * inv); p[3] = (half_t)(e[j][3] * inv);
        ((uint2*)rp)[lane + 64 * j] = *(const uint2*)p;
    }
}

// ---------------------------------------------------------------------------
// Transpose a[b] (C x HW, f32) -> fp16 At rows in the dead half of each packed
// S row (offset +1024 fp16). Runs AFTER softmax. grid (16,16,16). (unchanged)
// ---------------------------------------------------------------------------
__global__ __launch_bounds__(256) void k_transpose(const float* __restrict__ A,
                                                   half_t* __restrict__ SP) {
    const int bz = blockIdx.z;
    const int t0 = blockIdx.x * 64;  // HW block
    const int j0 = blockIdx.y * 64;  // C block
    const float* Ap = A + (size_t)bz * CDIM * HWDIM;
    half_t* Atp = SP + (size_t)bz * CDIM * PSTRIDE + 1024;

    __shared__ half_t tile[64][68];
    const int lr = threadIdx.x >> 4;         // 0..15
    const int lc = (threadIdx.x & 15) * 4;   // 0..60
#pragma unroll
    for (int r = 0; r < 4; ++r) {
        const float* src = Ap + (size_t)(j0 + lr + r * 16) * HWDIM + t0 + lc;
        float4 f = *(const float4*)src;
        half_t t4[4];
        t4[0] = (half_t)f.x; t4[1] = (half_t)f.y;
        t4[2] = (half_t)f.z; t4[3] = (half_t)f.w;
        *(uint2*)&tile[lr + r * 16][lc] = *(const uint2*)t4;
    }
    __syncthreads();
#pragma unroll
    for (int r = 0; r < 4; ++r) {
        const int trow = lr + r * 16;
        half_t tmp[4];
#pragma unroll
        for (int e = 0; e < 4; ++e) tmp[e] = tile[lc + e][trow];
        *(uint2*)(Atp + (size_t)(t0 + trow) * PSTRIDE + j0 + lc) = *(uint2*)tmp;
    }
}

// ---------------------------------------------------------------------------
// GEMM1: S[b][i][j] = sum_k bh[b][i][k] * ch[b][j][k]  (NT, fp16 in, f32 out)
// 256^2 8-phase. grid (16,16), block 512.
// ---------------------------------------------------------------------------
__global__ __launch_bounds__(512, 2) void k_gemm1(const half_t* __restrict__ Bh,
                                                  const half_t* __restrict__ Ch,
                                                  float* __restrict__ S) {
    __shared__ half_t lA[2 * TILE_E];
    __shared__ half_t lB[2 * TILE_E];
    int bz, i0, j0;
    tile_coords(bz, i0, j0);

    floatx4 acc[8][4];
    gemm8p(Bh + (size_t)bz * CDIM * HWDIM, HWDIM,
           Ch + (size_t)bz * CDIM * HWDIM, HWDIM, i0, j0, lA, lB, acc);

    float* Sp = S + (size_t)bz * CDIM * CDIM;
    const int lane = threadIdx.x & 63;
    const int wave = threadIdx.x >> 6;
    const int wm = wave >> 2, wn = wave & 3;
    const int er = (lane >> 4) * 4;
    const int ec = lane & 15;
#pragma unroll
    for (int mt = 0; mt < 8; ++mt) {
        const int row0 = i0 + ((mt >> 2) << 7) + wm * 64 + (mt & 3) * 16 + er;
#pragma unroll
        for (int nt = 0; nt < 4; ++nt) {
            const int col = j0 + ((nt >> 1) << 7) + wn * 32 + (nt & 1) * 16 + ec;
            float* dst = Sp + (size_t)row0 * CDIM + col;
#pragma unroll
            for (int r = 0; r < 4; ++r) dst[(size_t)r * CDIM] = acc[mt][nt][r];
        }
    }
}

// ---------------------------------------------------------------------------
// GEMM2: Out[b][i][t] = sum_j P[b][i][j]*At[b][t][j] + a[b][i][t] (f32 out).
// 256^2 8-phase. grid (16,16), block 512.
// ---------------------------------------------------------------------------
__global__ __launch_bounds__(512, 2) void k_gemm2(const half_t* __restrict__ SP,
                                                  const float* __restrict__ Aorig,
                                                  float* __restrict__ Out) {
    __shared__ half_t lA[2 * TILE_E];
    __shared__ half_t lB[2 * TILE_E];
    int bz, i0, t0;
    tile_coords(bz, i0, t0);

    const half_t* Pp = SP + (size_t)bz * CDIM * PSTRIDE;
    const half_t* Bp = Pp + 1024;  // At rows

    floatx4 acc[8][4];
    gemm8p(Pp, PSTRIDE, Bp, PSTRIDE, i0, t0, lA, lB, acc);

    const float* ap = Aorig + (size_t)bz * CDIM * HWDIM;
    float* op = Out + (size_t)bz * CDIM * HWDIM;
    const int lane = threadIdx.x & 63;
    const int wave = threadIdx.x >> 6;
    const int wm = wave >> 2, wn = wave & 3;
    const int er = (lane >> 4) * 4;
    const int ec = lane & 15;
#pragma unroll
    for (int mt = 0; mt < 8; ++mt) {
        const int row0 = i0 + ((mt >> 2) << 7) + wm * 64 + (mt & 3) * 16 + er;
#pragma unroll
        for (int nt = 0; nt < 4; ++nt) {
            const int col = t0 + ((nt >> 1) << 7) + wn * 32 + (nt & 1) * 16 + ec;
#pragma unroll
            for (int r = 0; r < 4; ++r) {
                const size_t idx = (size_t)(row0 + r) * HWDIM + col;
                op[idx] = acc[mt][nt][r] + ap[idx];
            }
        }
    }
}

extern "C" void kernel_launch(void* const* d_in, const int* in_sizes, int n_in,
                              void* d_out, int out_size, void* d_ws, size_t ws_size,
                              hipStream_t stream) {
    const float* a = (const float*)d_in[0];
    const float* b = (const float*)d_in[1];
    const float* c = (const float*)d_in[2];
    float* out = (float*)d_out;

    float* S = (float*)d_ws;            // 64 MB: fp32 scores -> {P | At} packed
    half_t* bc16 = (half_t*)d_out;      // d_out doubles as fp16 scratch for b,c
                                        // (gemm2 fully overwrites it at the end)

    k_prep<<<dim3(2048, 2), 256, 0, stream>>>(b, c, bc16);
    k_gemm1<<<dim3(16, 16), 512, 0, stream>>>(
        bc16, bc16 + (size_t)BATCH * CDIM * HWDIM, S);
    k_softmax<<<dim3(BATCH * CDIM / 4), 256, 0, stream>>>(S);
    k_transpose<<<dim3(16, 16, 16), 256, 0, stream>>>(a, (half_t*)S);
    k_gemm2<<<dim3(16, 16), 512, 0, stream>>>((const half_t*)S, a, out);
}